// Round 8
// baseline (49.174 us; speedup 1.0000x reference)
//
#include <hip/hip_runtime.h>
#include <hip/hip_bf16.h>

#define BATCH 4
#define NB    256
#define NE    (NB*(NB-1))   // 65280

typedef short    short8 __attribute__((ext_vector_type(8)));
typedef float    f32x16 __attribute__((ext_vector_type(16)));

static __device__ __forceinline__ short f2bf(float x) {
    return __builtin_bit_cast(short, __float2bfloat16(x));   // RNE
}
static __device__ __forceinline__ float bf2f(short s) {
    unsigned u = ((unsigned)(unsigned short)s) << 16;
    return __builtin_bit_cast(float, u);
}
static __device__ __forceinline__ f32x16 splat16(float v) {
    f32x16 r;
    #pragma unroll
    for (int e = 0; e < 16; ++e) r[e] = v;
    return r;
}

#define MFMA(C, A, B) C = __builtin_amdgcn_mfma_f32_32x32x16_bf16(A, B, C, 0, 0, 0)

// W1 B-frag from LDS f32 (stride-64 scalar LDS reads: consecutive lanes ->
// consecutive banks, conflict-free; lane vs lane+32 2-way = free)
#define MK_BW(dst, BASE, K0, NT) do {                                          \
    const float* _p = W1l + (BASE) + (16*(K0) + 8*lh) * 64 + l31 + 32*(NT);    \
    short8 _v;                                                                 \
    _v[0]=f2bf(_p[0]);   _v[1]=f2bf(_p[64]);  _v[2]=f2bf(_p[128]);             \
    _v[3]=f2bf(_p[192]); _v[4]=f2bf(_p[256]); _v[5]=f2bf(_p[320]);             \
    _v[6]=f2bf(_p[384]); _v[7]=f2bf(_p[448]);                                  \
    (dst) = _v; } while (0)

// ---------------------------------------------------------------------------
// prep (17 wgs): blk<16 = (i, b, node-half): x,W1 staged to LDS (coalesced),
// fragments built from LDS, node GEMMs via MFMA -> Pbf (frag layout) + Qg.
// blk==16 = W2 -> bf16 B-fragments.
//   Pbf [i*4+b][hb][n][8] bf16 : P = x·W1[:64]
//   Qg  [i*4+b][n][64]   f32   : x·W1[64:] + b1
//   W2f [2][2][4][64][8] bf16
// ---------------------------------------------------------------------------
__global__ __launch_bounds__(256) void prep_kernel(
    const float* __restrict__ x,   // [B][N][64]
    const float* __restrict__ W1,  // [2][128][64]
    const float* __restrict__ b1,  // [2][64]
    const float* __restrict__ W2,  // [2][64][64]
    short* __restrict__ Pbf,
    float* __restrict__ Qg,
    short* __restrict__ W2f)
{
    const int t    = threadIdx.x;
    const int lane = t & 63;
    const int w    = t >> 6;
    const int l31  = lane & 31;
    const int lh   = lane >> 5;
    const int blk  = blockIdx.x;

    __shared__ __align__(16) float W1l[8192];   // 32 KiB: W1[i] full
    __shared__ __align__(16) short xbf[8192];   // 16 KiB: 128 x-rows bf16, swizzled

    if (blk < 16) {
        const int i    = blk >> 3;
        const int b    = (blk >> 1) & 3;
        const int half = blk & 1;
        const int n0   = half * 128;
        const int ibb  = i * 4 + b;
        const float* xb = x + (size_t)b * NB * 64;

        // stage W1[i] (coalesced float4)
        #pragma unroll
        for (int q = 0; q < 8; ++q) {
            const int e = (q * 256 + t) * 4;
            *(float4*)(W1l + e) = *(const float4*)(W1 + (size_t)i * 8192 + e);
        }
        // stage 128 x-rows as bf16, XOR-swizzled (16B chunk granularity)
        #pragma unroll
        for (int rep = 0; rep < 2; ++rep) {
            const int n  = (t >> 2) + 64 * rep;        // local row 0..127
            const int f0 = (t & 3) * 16;
            const float* src = xb + (n0 + n) * 64 + f0;
            float4 v0 = *(const float4*)(src);
            float4 v1 = *(const float4*)(src + 4);
            float4 v2 = *(const float4*)(src + 8);
            float4 v3 = *(const float4*)(src + 12);
            short8 s0 = { f2bf(v0.x), f2bf(v0.y), f2bf(v0.z), f2bf(v0.w),
                          f2bf(v1.x), f2bf(v1.y), f2bf(v1.z), f2bf(v1.w) };
            short8 s1 = { f2bf(v2.x), f2bf(v2.y), f2bf(v2.z), f2bf(v2.w),
                          f2bf(v3.x), f2bf(v3.y), f2bf(v3.z), f2bf(v3.w) };
            const int sw = (n & 7) << 4;
            *(short8*)((char*)xbf + n * 128 + ((f0 * 2)      ^ sw)) = s0;
            *(short8*)((char*)xbf + n * 128 + ((f0 * 2 + 16) ^ sw)) = s1;
        }
        __syncthreads();

        // per-wave A-operand: its 32 node rows, from swizzled LDS (conflict-free)
        const int rloc = 32 * w + l31;
        const int swr  = (rloc & 7) << 4;
        const short8 XB0 = *(const short8*)((const char*)xbf + rloc*128 + ((16*lh)       ^ swr));
        const short8 XB1 = *(const short8*)((const char*)xbf + rloc*128 + ((32 + 16*lh)  ^ swr));
        const short8 XB2 = *(const short8*)((const char*)xbf + rloc*128 + ((64 + 16*lh)  ^ swr));
        const short8 XB3 = *(const short8*)((const char*)xbf + rloc*128 + ((96 + 16*lh)  ^ swr));

        // ---- P, N-tile 0 (hh = l31) ----
        {
            short8 B0, B1, B2, B3;
            MK_BW(B0, 0, 0, 0); MK_BW(B1, 0, 1, 0); MK_BW(B2, 0, 2, 0); MK_BW(B3, 0, 3, 0);
            f32x16 c = splat16(0.f);
            MFMA(c, XB0, B0); MFMA(c, XB1, B1); MFMA(c, XB2, B2); MFMA(c, XB3, B3);
            #pragma unroll
            for (int rg = 0; rg < 16; ++rg) {
                const int nn = n0 + 32*w + (rg & 3) + 8*(rg >> 2) + 4*lh;
                Pbf[(size_t)ibb*16384 + (l31 >> 3)*2048 + nn*8 + (l31 & 7)] = f2bf(c[rg]);
            }
        }
        // ---- P, N-tile 1 (hh = l31 + 32) ----
        {
            short8 B0, B1, B2, B3;
            MK_BW(B0, 0, 0, 1); MK_BW(B1, 0, 1, 1); MK_BW(B2, 0, 2, 1); MK_BW(B3, 0, 3, 1);
            f32x16 c = splat16(0.f);
            MFMA(c, XB0, B0); MFMA(c, XB1, B1); MFMA(c, XB2, B2); MFMA(c, XB3, B3);
            #pragma unroll
            for (int rg = 0; rg < 16; ++rg) {
                const int nn = n0 + 32*w + (rg & 3) + 8*(rg >> 2) + 4*lh;
                Pbf[(size_t)ibb*16384 + (4 + (l31 >> 3))*2048 + nn*8 + (l31 & 7)] = f2bf(c[rg]);
            }
        }
        // ---- Q, N-tile 0 ----
        {
            short8 B0, B1, B2, B3;
            MK_BW(B0, 4096, 0, 0); MK_BW(B1, 4096, 1, 0); MK_BW(B2, 4096, 2, 0); MK_BW(B3, 4096, 3, 0);
            f32x16 c = splat16(0.f);
            MFMA(c, XB0, B0); MFMA(c, XB1, B1); MFMA(c, XB2, B2); MFMA(c, XB3, B3);
            const float b1v = b1[i * 64 + l31];
            #pragma unroll
            for (int rg = 0; rg < 16; ++rg) {
                const int nn = n0 + 32*w + (rg & 3) + 8*(rg >> 2) + 4*lh;
                Qg[(size_t)ibb*16384 + nn*64 + l31] = c[rg] + b1v;
            }
        }
        // ---- Q, N-tile 1 ----
        {
            short8 B0, B1, B2, B3;
            MK_BW(B0, 4096, 0, 1); MK_BW(B1, 4096, 1, 1); MK_BW(B2, 4096, 2, 1); MK_BW(B3, 4096, 3, 1);
            f32x16 c = splat16(0.f);
            MFMA(c, XB0, B0); MFMA(c, XB1, B1); MFMA(c, XB2, B2); MFMA(c, XB3, B3);
            const float b1v = b1[i * 64 + 32 + l31];
            #pragma unroll
            for (int rg = 0; rg < 16; ++rg) {
                const int nn = n0 + 32*w + (rg & 3) + 8*(rg >> 2) + 4*lh;
                Qg[(size_t)ibb*16384 + nn*64 + 32 + l31] = c[rg] + b1v;
            }
        }
    } else {
        // W2 -> fragments, source-coalesced reads, small scatter writes
        #pragma unroll
        for (int q = 0; q < 32; ++q) {
            const int e = q * 256 + t;             // == i*4096 + k*64 + n
            const int i = e >> 12, k = (e >> 6) & 63, n = e & 63;
            const float v = W2[e];
            const int k0 = k >> 4, j = k & 7, hm = (k >> 3) & 1;
            const int nt = n >> 5;
            W2f[(((i*2 + nt)*4 + k0)*64 + hm*32 + (n & 31))*8 + j] = f2bf(v);
        }
    }
}

// ---------------------------------------------------------------------------
// main: one wg per (b, receiver r); 256 threads = 4 waves; VGPR<=128 so all
// 1024 wgs are co-resident (4 wg/CU, 4 waves/SIMD). Edge work only.
// ---------------------------------------------------------------------------

// A2 frag: relu(bf2f(P) + qrow) -> bf16, k-elems h = 16*K0+8*lh+j
#define MK_A2(dst, PV, I, K0) do {                                             \
    float4 _q0 = *(const float4*)(&qrow[I][16*(K0) + 8*lh]);                   \
    float4 _q1 = *(const float4*)(&qrow[I][16*(K0) + 8*lh + 4]);               \
    short8 _v;                                                                 \
    _v[0] = f2bf(fmaxf(bf2f((PV)[0]) + _q0.x, 0.f));                           \
    _v[1] = f2bf(fmaxf(bf2f((PV)[1]) + _q0.y, 0.f));                           \
    _v[2] = f2bf(fmaxf(bf2f((PV)[2]) + _q0.z, 0.f));                           \
    _v[3] = f2bf(fmaxf(bf2f((PV)[3]) + _q0.w, 0.f));                           \
    _v[4] = f2bf(fmaxf(bf2f((PV)[4]) + _q1.x, 0.f));                           \
    _v[5] = f2bf(fmaxf(bf2f((PV)[5]) + _q1.y, 0.f));                           \
    _v[6] = f2bf(fmaxf(bf2f((PV)[6]) + _q1.z, 0.f));                           \
    _v[7] = f2bf(fmaxf(bf2f((PV)[7]) + _q1.w, 0.f));                           \
    (dst) = _v; } while (0)

#define EPI_QD(C2A, C2B, I, ET, QD) do {                                       \
    float4 _rq = *(const float4*)(&rt2[I][64*w + 32*(ET) + 8*(QD) + 4*lh]);    \
    psum0 += fmaxf((C2A)[4*(QD)],   0.f) * _rq.x;                              \
    psum0 += fmaxf((C2A)[4*(QD)+1], 0.f) * _rq.y;                              \
    psum0 += fmaxf((C2A)[4*(QD)+2], 0.f) * _rq.z;                              \
    psum0 += fmaxf((C2A)[4*(QD)+3], 0.f) * _rq.w;                              \
    psum1 += fmaxf((C2B)[4*(QD)],   0.f) * _rq.x;                              \
    psum1 += fmaxf((C2B)[4*(QD)+1], 0.f) * _rq.y;                              \
    psum1 += fmaxf((C2B)[4*(QD)+2], 0.f) * _rq.z;                              \
    psum1 += fmaxf((C2B)[4*(QD)+3], 0.f) * _rq.w; } while (0)

// interleaved A2-build / MFMA: only one a2 fragment live at a time
#define TILE2(I, ET, PA, PB, PC, PD, BVA, BVB) do {                            \
    f32x16 _c2a = splat16(BVA), _c2b = splat16(BVB);                           \
    short8 _a, _w0, _w4;                                                       \
    MK_A2(_a, PA, I, 0);                                                       \
    _w0 = *(const short8*)(W2l + (((I)*8 + 0)*64 + lane)*8);                   \
    _w4 = *(const short8*)(W2l + (((I)*8 + 4)*64 + lane)*8);                   \
    MFMA(_c2a, _a, _w0); MFMA(_c2b, _a, _w4);                                  \
    MK_A2(_a, PB, I, 1);                                                       \
    _w0 = *(const short8*)(W2l + (((I)*8 + 1)*64 + lane)*8);                   \
    _w4 = *(const short8*)(W2l + (((I)*8 + 5)*64 + lane)*8);                   \
    MFMA(_c2a, _a, _w0); MFMA(_c2b, _a, _w4);                                  \
    MK_A2(_a, PC, I, 2);                                                       \
    _w0 = *(const short8*)(W2l + (((I)*8 + 2)*64 + lane)*8);                   \
    _w4 = *(const short8*)(W2l + (((I)*8 + 6)*64 + lane)*8);                   \
    MFMA(_c2a, _a, _w0); MFMA(_c2b, _a, _w4);                                  \
    MK_A2(_a, PD, I, 3);                                                       \
    _w0 = *(const short8*)(W2l + (((I)*8 + 3)*64 + lane)*8);                   \
    _w4 = *(const short8*)(W2l + (((I)*8 + 7)*64 + lane)*8);                   \
    MFMA(_c2a, _a, _w0); MFMA(_c2b, _a, _w4);                                  \
    EPI_QD(_c2a, _c2b, I, ET, 0); EPI_QD(_c2a, _c2b, I, ET, 1);                \
    EPI_QD(_c2a, _c2b, I, ET, 2); EPI_QD(_c2a, _c2b, I, ET, 3); } while (0)

#define LD_P(I, K0, S) \
    (*(const short8*)(PbfG + ((size_t)((I)*4+b)*8 + 2*(K0)+lh)*2048 + (size_t)(S)*8))

__global__ __launch_bounds__(256, 4) void main_kernel(
    const float* __restrict__ x,
    const float* __restrict__ rel_type, // [B][E][2]
    const float* __restrict__ b2,       // [2][64]
    const float* __restrict__ Wo1,      // [128][64]
    const float* __restrict__ bo1,
    const float* __restrict__ Wo2,      // [64][64]
    const float* __restrict__ bo2,
    const short* __restrict__ PbfG,
    const float* __restrict__ Qg,
    const short* __restrict__ W2fG,
    float* __restrict__ out)
{
    const int b    = blockIdx.x >> 8;
    const int r    = blockIdx.x & 255;
    const int t    = threadIdx.x;
    const int lane = t & 63;
    const int w    = t >> 6;
    const int l31  = lane & 31;
    const int lh   = lane >> 5;

    __shared__ __align__(16) short W2l[8192];      // 16 KiB
    __shared__ __align__(16) float rt2[2][256];
    __shared__ __align__(16) float qrow[2][64];
    __shared__ __align__(16) float red[4][64];
    __shared__ __align__(16) float xl[64];
    __shared__ __align__(16) float aggl[64];
    __shared__ __align__(16) float predl[64];

    const float* xb = x + (size_t)b * NB * 64;

    // ---- staging ----
    if (t < 255) {
        const float2 pv = *(const float2*)(rel_type + ((size_t)b * NE + (size_t)r * 255 + t) * 2);
        rt2[0][t] = pv.x;
        rt2[1][t] = pv.y;
    } else {
        rt2[0][255] = 0.f; rt2[1][255] = 0.f;      // pad edge contributes 0
    }
    #pragma unroll
    for (int q = 0; q < 4; ++q) {                  // W2 frags -> LDS (b128 copy)
        const int e = (q * 256 + t) * 8;
        *(short8*)(W2l + e) = *(const short8*)(W2fG + e);
    }
    if (t < 128) {
        const int i = t >> 6, h = t & 63;
        qrow[i][h] = Qg[(size_t)(i * 4 + b) * 16384 + r * 64 + h];
    }
    if (t >= 192) xl[t - 192] = xb[r * 64 + (t - 192)];

    // edge rows for this wave's two M-tiles
    const int kap0 = 64 * w + l31;
    const int kap1 = kap0 + 32;
    int s0 = (kap0 < r) ? kap0 : kap0 + 1; if (s0 > 255) s0 = 255;  // pad row
    int s1 = (kap1 < r) ? kap1 : kap1 + 1; if (s1 > 255) s1 = 255;

    // type-0 P gathers only (type-1 prefetched later: keeps VGPR <= 128)
    short8 P000 = LD_P(0,0,s0), P001 = LD_P(0,1,s0), P002 = LD_P(0,2,s0), P003 = LD_P(0,3,s0);
    short8 P010 = LD_P(0,0,s1), P011 = LD_P(0,1,s1), P012 = LD_P(0,2,s1), P013 = LD_P(0,3,s1);

    const float bv00 = b2[l31],      bv01 = b2[32 + l31];
    const float bv10 = b2[64 + l31], bv11 = b2[96 + l31];

    __syncthreads();

    float psum0 = 0.f, psum1 = 0.f;   // per-lane agg partials, h = l31 / l31+32

    TILE2(0, 0, P000, P001, P002, P003, bv00, bv01);
    TILE2(0, 1, P010, P011, P012, P013, bv00, bv01);

    {   // type-1 P gathers (reuse register space freed by type-0 frags)
        short8 Q000 = LD_P(1,0,s0), Q001 = LD_P(1,1,s0), Q002 = LD_P(1,2,s0), Q003 = LD_P(1,3,s0);
        short8 Q010 = LD_P(1,0,s1), Q011 = LD_P(1,1,s1), Q012 = LD_P(1,2,s1), Q013 = LD_P(1,3,s1);
        TILE2(1, 0, Q000, Q001, Q002, Q003, bv10, bv11);
        TILE2(1, 1, Q010, Q011, Q012, Q013, bv10, bv11);
    }

    // ---- reduce: lane-halves, then waves ----
    psum0 += __shfl_xor(psum0, 32, 64);
    psum1 += __shfl_xor(psum1, 32, 64);
    if (lh == 0) {
        red[w][l31]      = psum0;
        red[w][l31 + 32] = psum1;
    }
    __syncthreads();
    if (t < 64) aggl[t] = red[0][t] + red[1][t] + red[2][t] + red[3][t];
    __syncthreads();

    // ---- output MLP layer 1: aug(128) @ Wo1(128x64) ----
    {
        const float* src = (w < 2) ? (xl + w * 32) : (aggl + (w - 2) * 32);
        const float* Wp  = Wo1 + (w * 32) * 64 + lane;
        float s = 0.f;
        #pragma unroll
        for (int jj = 0; jj < 32; ++jj) s = fmaf(src[jj], Wp[jj * 64], s);
        red[w][lane] = s;
    }
    __syncthreads();
    if (t < 64)
        predl[t] = fmaxf(red[0][t] + red[1][t] + red[2][t] + red[3][t] + bo1[t], 0.f);
    __syncthreads();

    // ---- output MLP layer 2 + residual ----
    {
        const float* Wp = Wo2 + (w * 16) * 64 + lane;
        float s = 0.f;
        #pragma unroll
        for (int jj = 0; jj < 16; ++jj) s = fmaf(predl[w * 16 + jj], Wp[jj * 64], s);
        red[w][lane] = s;
    }
    __syncthreads();
    if (t < 64)
        out[((size_t)b * NB + r) * 64 + t] =
            xl[t] + fmaxf(red[0][t] + red[1][t] + red[2][t] + red[3][t] + bo2[t], 0.f);
}

// ---------------------------------------------------------------------------
extern "C" void kernel_launch(void* const* d_in, const int* in_sizes, int n_in,
                              void* d_out, int out_size, void* d_ws, size_t ws_size,
                              hipStream_t stream) {
    (void)in_sizes; (void)n_in; (void)out_size; (void)ws_size;

    const float* x    = (const float*)d_in[0];
    const float* rt   = (const float*)d_in[1];
    // d_in[2] = rel_rec, d_in[3] = rel_send: dense all-pairs one-hot, unused
    const float* W1   = (const float*)d_in[4];
    const float* b1   = (const float*)d_in[5];
    const float* W2   = (const float*)d_in[6];
    const float* b2   = (const float*)d_in[7];
    const float* Wo1  = (const float*)d_in[8];
    const float* bo1  = (const float*)d_in[9];
    const float* Wo2  = (const float*)d_in[10];
    const float* bo2  = (const float*)d_in[11];
    float* out = (float*)d_out;

    char* ws = (char*)d_ws;
    short* Pbf = (short*)ws;                 // 8*16384*2B  = 256 KiB
    float* Qg  = (float*)(ws + 262144);      // 8*16384*4B  = 512 KiB
    short* W2f = (short*)(ws + 786432);      // 16 KiB

    prep_kernel<<<17, 256, 0, stream>>>(x, W1, b1, W2, Pbf, Qg, W2f);
    main_kernel<<<BATCH * NB, 256, 0, stream>>>(x, rt, b2, Wo1, bo1, Wo2, bo2,
                                                Pbf, Qg, W2f, out);
}

// Round 9
// 23.698 us; speedup vs baseline: 2.0750x; 2.0750x over previous
//
#include <hip/hip_runtime.h>
#include <hip/hip_bf16.h>

#define BATCH 4
#define NB    256
#define NE    (NB*(NB-1))   // 65280

typedef short    short8 __attribute__((ext_vector_type(8)));
typedef float    f32x16 __attribute__((ext_vector_type(16)));

static __device__ __forceinline__ short f2bf(float x) {
    return __builtin_bit_cast(short, __float2bfloat16(x));   // RNE
}
static __device__ __forceinline__ float bf2f(short s) {
    unsigned u = ((unsigned)(unsigned short)s) << 16;
    return __builtin_bit_cast(float, u);
}
static __device__ __forceinline__ f32x16 splat16(float v) {
    f32x16 r;
    #pragma unroll
    for (int e = 0; e < 16; ++e) r[e] = v;
    return r;
}

#define MFMA(C, A, B) C = __builtin_amdgcn_mfma_f32_32x32x16_bf16(A, B, C, 0, 0, 0)

// W1 B-frag from LDS f32 (stride-64 scalar LDS reads: consecutive lanes ->
// consecutive banks, conflict-free; lane vs lane+32 2-way = free)
#define MK_BW(dst, BASE, K0, NT) do {                                          \
    const float* _p = W1l + (BASE) + (16*(K0) + 8*lh) * 64 + l31 + 32*(NT);    \
    short8 _v;                                                                 \
    _v[0]=f2bf(_p[0]);   _v[1]=f2bf(_p[64]);  _v[2]=f2bf(_p[128]);             \
    _v[3]=f2bf(_p[192]); _v[4]=f2bf(_p[256]); _v[5]=f2bf(_p[320]);             \
    _v[6]=f2bf(_p[384]); _v[7]=f2bf(_p[448]);                                  \
    (dst) = _v; } while (0)

// ---------------------------------------------------------------------------
// prep (17 wgs): blk<16 = (i, b, node-half): x,W1 staged to LDS (coalesced),
// fragments built from LDS, node GEMMs via MFMA -> Pbf (frag layout) + Qg.
// blk==16 = W2 -> bf16 B-fragments.  (unchanged from R7 — proven)
// ---------------------------------------------------------------------------
__global__ __launch_bounds__(256) void prep_kernel(
    const float* __restrict__ x,   // [B][N][64]
    const float* __restrict__ W1,  // [2][128][64]
    const float* __restrict__ b1,  // [2][64]
    const float* __restrict__ W2,  // [2][64][64]
    short* __restrict__ Pbf,
    float* __restrict__ Qg,
    short* __restrict__ W2f)
{
    const int t    = threadIdx.x;
    const int lane = t & 63;
    const int w    = t >> 6;
    const int l31  = lane & 31;
    const int lh   = lane >> 5;
    const int blk  = blockIdx.x;

    __shared__ __align__(16) float W1l[8192];   // 32 KiB: W1[i] full
    __shared__ __align__(16) short xbf[8192];   // 16 KiB: 128 x-rows bf16, swizzled

    if (blk < 16) {
        const int i    = blk >> 3;
        const int b    = (blk >> 1) & 3;
        const int half = blk & 1;
        const int n0   = half * 128;
        const int ibb  = i * 4 + b;
        const float* xb = x + (size_t)b * NB * 64;

        #pragma unroll
        for (int q = 0; q < 8; ++q) {
            const int e = (q * 256 + t) * 4;
            *(float4*)(W1l + e) = *(const float4*)(W1 + (size_t)i * 8192 + e);
        }
        #pragma unroll
        for (int rep = 0; rep < 2; ++rep) {
            const int n  = (t >> 2) + 64 * rep;        // local row 0..127
            const int f0 = (t & 3) * 16;
            const float* src = xb + (n0 + n) * 64 + f0;
            float4 v0 = *(const float4*)(src);
            float4 v1 = *(const float4*)(src + 4);
            float4 v2 = *(const float4*)(src + 8);
            float4 v3 = *(const float4*)(src + 12);
            short8 s0 = { f2bf(v0.x), f2bf(v0.y), f2bf(v0.z), f2bf(v0.w),
                          f2bf(v1.x), f2bf(v1.y), f2bf(v1.z), f2bf(v1.w) };
            short8 s1 = { f2bf(v2.x), f2bf(v2.y), f2bf(v2.z), f2bf(v2.w),
                          f2bf(v3.x), f2bf(v3.y), f2bf(v3.z), f2bf(v3.w) };
            const int sw = (n & 7) << 4;
            *(short8*)((char*)xbf + n * 128 + ((f0 * 2)      ^ sw)) = s0;
            *(short8*)((char*)xbf + n * 128 + ((f0 * 2 + 16) ^ sw)) = s1;
        }
        __syncthreads();

        const int rloc = 32 * w + l31;
        const int swr  = (rloc & 7) << 4;
        const short8 XB0 = *(const short8*)((const char*)xbf + rloc*128 + ((16*lh)       ^ swr));
        const short8 XB1 = *(const short8*)((const char*)xbf + rloc*128 + ((32 + 16*lh)  ^ swr));
        const short8 XB2 = *(const short8*)((const char*)xbf + rloc*128 + ((64 + 16*lh)  ^ swr));
        const short8 XB3 = *(const short8*)((const char*)xbf + rloc*128 + ((96 + 16*lh)  ^ swr));

        {   // P, N-tile 0 (hh = l31)
            short8 B0, B1, B2, B3;
            MK_BW(B0, 0, 0, 0); MK_BW(B1, 0, 1, 0); MK_BW(B2, 0, 2, 0); MK_BW(B3, 0, 3, 0);
            f32x16 c = splat16(0.f);
            MFMA(c, XB0, B0); MFMA(c, XB1, B1); MFMA(c, XB2, B2); MFMA(c, XB3, B3);
            #pragma unroll
            for (int rg = 0; rg < 16; ++rg) {
                const int nn = n0 + 32*w + (rg & 3) + 8*(rg >> 2) + 4*lh;
                Pbf[(size_t)ibb*16384 + (l31 >> 3)*2048 + nn*8 + (l31 & 7)] = f2bf(c[rg]);
            }
        }
        {   // P, N-tile 1 (hh = l31 + 32)
            short8 B0, B1, B2, B3;
            MK_BW(B0, 0, 0, 1); MK_BW(B1, 0, 1, 1); MK_BW(B2, 0, 2, 1); MK_BW(B3, 0, 3, 1);
            f32x16 c = splat16(0.f);
            MFMA(c, XB0, B0); MFMA(c, XB1, B1); MFMA(c, XB2, B2); MFMA(c, XB3, B3);
            #pragma unroll
            for (int rg = 0; rg < 16; ++rg) {
                const int nn = n0 + 32*w + (rg & 3) + 8*(rg >> 2) + 4*lh;
                Pbf[(size_t)ibb*16384 + (4 + (l31 >> 3))*2048 + nn*8 + (l31 & 7)] = f2bf(c[rg]);
            }
        }
        {   // Q, N-tile 0
            short8 B0, B1, B2, B3;
            MK_BW(B0, 4096, 0, 0); MK_BW(B1, 4096, 1, 0); MK_BW(B2, 4096, 2, 0); MK_BW(B3, 4096, 3, 0);
            f32x16 c = splat16(0.f);
            MFMA(c, XB0, B0); MFMA(c, XB1, B1); MFMA(c, XB2, B2); MFMA(c, XB3, B3);
            const float b1v = b1[i * 64 + l31];
            #pragma unroll
            for (int rg = 0; rg < 16; ++rg) {
                const int nn = n0 + 32*w + (rg & 3) + 8*(rg >> 2) + 4*lh;
                Qg[(size_t)ibb*16384 + nn*64 + l31] = c[rg] + b1v;
            }
        }
        {   // Q, N-tile 1
            short8 B0, B1, B2, B3;
            MK_BW(B0, 4096, 0, 1); MK_BW(B1, 4096, 1, 1); MK_BW(B2, 4096, 2, 1); MK_BW(B3, 4096, 3, 1);
            f32x16 c = splat16(0.f);
            MFMA(c, XB0, B0); MFMA(c, XB1, B1); MFMA(c, XB2, B2); MFMA(c, XB3, B3);
            const float b1v = b1[i * 64 + 32 + l31];
            #pragma unroll
            for (int rg = 0; rg < 16; ++rg) {
                const int nn = n0 + 32*w + (rg & 3) + 8*(rg >> 2) + 4*lh;
                Qg[(size_t)ibb*16384 + nn*64 + 32 + l31] = c[rg] + b1v;
            }
        }
    } else {
        #pragma unroll
        for (int q = 0; q < 32; ++q) {
            const int e = q * 256 + t;             // == i*4096 + k*64 + n
            const int i = e >> 12, k = (e >> 6) & 63, n = e & 63;
            const float v = W2[e];
            const int k0 = k >> 4, j = k & 7, hm = (k >> 3) & 1;
            const int nt = n >> 5;
            W2f[(((i*2 + nt)*4 + k0)*64 + hm*32 + (n & 31))*8 + j] = f2bf(v);
        }
    }
}

// ---------------------------------------------------------------------------
// main: one wg per (b, receiver r); 256 threads = 4 waves. Register-lean:
// single live A2 fragment, JIT type-1 P loads pipelined under type-0 MFMA.
// NO launch-bounds min-waves (R8: forcing it caused a 108 MB spill storm).
// ---------------------------------------------------------------------------

// A2 frag: relu(bf2f(P) + qrow) -> bf16, k-elems h = 16*K0+8*lh+j
#define MK_A2(dst, PV, I, K0) do {                                             \
    float4 _q0 = *(const float4*)(&qrow[I][16*(K0) + 8*lh]);                   \
    float4 _q1 = *(const float4*)(&qrow[I][16*(K0) + 8*lh + 4]);               \
    short8 _v;                                                                 \
    _v[0] = f2bf(fmaxf(bf2f((PV)[0]) + _q0.x, 0.f));                           \
    _v[1] = f2bf(fmaxf(bf2f((PV)[1]) + _q0.y, 0.f));                           \
    _v[2] = f2bf(fmaxf(bf2f((PV)[2]) + _q0.z, 0.f));                           \
    _v[3] = f2bf(fmaxf(bf2f((PV)[3]) + _q0.w, 0.f));                           \
    _v[4] = f2bf(fmaxf(bf2f((PV)[4]) + _q1.x, 0.f));                           \
    _v[5] = f2bf(fmaxf(bf2f((PV)[5]) + _q1.y, 0.f));                           \
    _v[6] = f2bf(fmaxf(bf2f((PV)[6]) + _q1.z, 0.f));                           \
    _v[7] = f2bf(fmaxf(bf2f((PV)[7]) + _q1.w, 0.f));                           \
    (dst) = _v; } while (0)

#define EPI_QD(C2A, C2B, I, ET, QD) do {                                       \
    float4 _rq = *(const float4*)(&rt2[I][64*w + 32*(ET) + 8*(QD) + 4*lh]);    \
    psum0 += fmaxf((C2A)[4*(QD)],   0.f) * _rq.x;                              \
    psum0 += fmaxf((C2A)[4*(QD)+1], 0.f) * _rq.y;                              \
    psum0 += fmaxf((C2A)[4*(QD)+2], 0.f) * _rq.z;                              \
    psum0 += fmaxf((C2A)[4*(QD)+3], 0.f) * _rq.w;                              \
    psum1 += fmaxf((C2B)[4*(QD)],   0.f) * _rq.x;                              \
    psum1 += fmaxf((C2B)[4*(QD)+1], 0.f) * _rq.y;                              \
    psum1 += fmaxf((C2B)[4*(QD)+2], 0.f) * _rq.z;                              \
    psum1 += fmaxf((C2B)[4*(QD)+3], 0.f) * _rq.w; } while (0)

// interleaved A2-build / MFMA: only one a2 fragment live at a time
#define TILE2(I, ET, PA, PB, PC, PD, BVA, BVB) do {                            \
    f32x16 _c2a = splat16(BVA), _c2b = splat16(BVB);                           \
    short8 _a, _w0, _w4;                                                       \
    MK_A2(_a, PA, I, 0);                                                       \
    _w0 = *(const short8*)(W2l + (((I)*8 + 0)*64 + lane)*8);                   \
    _w4 = *(const short8*)(W2l + (((I)*8 + 4)*64 + lane)*8);                   \
    MFMA(_c2a, _a, _w0); MFMA(_c2b, _a, _w4);                                  \
    MK_A2(_a, PB, I, 1);                                                       \
    _w0 = *(const short8*)(W2l + (((I)*8 + 1)*64 + lane)*8);                   \
    _w4 = *(const short8*)(W2l + (((I)*8 + 5)*64 + lane)*8);                   \
    MFMA(_c2a, _a, _w0); MFMA(_c2b, _a, _w4);                                  \
    MK_A2(_a, PC, I, 2);                                                       \
    _w0 = *(const short8*)(W2l + (((I)*8 + 2)*64 + lane)*8);                   \
    _w4 = *(const short8*)(W2l + (((I)*8 + 6)*64 + lane)*8);                   \
    MFMA(_c2a, _a, _w0); MFMA(_c2b, _a, _w4);                                  \
    MK_A2(_a, PD, I, 3);                                                       \
    _w0 = *(const short8*)(W2l + (((I)*8 + 3)*64 + lane)*8);                   \
    _w4 = *(const short8*)(W2l + (((I)*8 + 7)*64 + lane)*8);                   \
    MFMA(_c2a, _a, _w0); MFMA(_c2b, _a, _w4);                                  \
    EPI_QD(_c2a, _c2b, I, ET, 0); EPI_QD(_c2a, _c2b, I, ET, 1);                \
    EPI_QD(_c2a, _c2b, I, ET, 2); EPI_QD(_c2a, _c2b, I, ET, 3); } while (0)

#define LD_P(I, K0, S) \
    (*(const short8*)(PbfG + ((size_t)((I)*4+b)*8 + 2*(K0)+lh)*2048 + (size_t)(S)*8))

__global__ __launch_bounds__(256) void main_kernel(
    const float* __restrict__ x,
    const float* __restrict__ rel_type, // [B][E][2]
    const float* __restrict__ b2,       // [2][64]
    const float* __restrict__ Wo1,      // [128][64]
    const float* __restrict__ bo1,
    const float* __restrict__ Wo2,      // [64][64]
    const float* __restrict__ bo2,
    const short* __restrict__ PbfG,
    const float* __restrict__ Qg,
    const short* __restrict__ W2fG,
    float* __restrict__ out)
{
    const int b    = blockIdx.x >> 8;
    const int r    = blockIdx.x & 255;
    const int t    = threadIdx.x;
    const int lane = t & 63;
    const int w    = t >> 6;
    const int l31  = lane & 31;
    const int lh   = lane >> 5;

    __shared__ __align__(16) short W2l[8192];      // 16 KiB
    __shared__ __align__(16) float rt2[2][256];
    __shared__ __align__(16) float qrow[2][64];
    __shared__ __align__(16) float red[4][64];
    __shared__ __align__(16) float xl[64];
    __shared__ __align__(16) float aggl[64];
    __shared__ __align__(16) float predl[64];

    const float* xb = x + (size_t)b * NB * 64;

    // ---- staging ----
    if (t < 255) {
        const float2 pv = *(const float2*)(rel_type + ((size_t)b * NE + (size_t)r * 255 + t) * 2);
        rt2[0][t] = pv.x;
        rt2[1][t] = pv.y;
    } else {
        rt2[0][255] = 0.f; rt2[1][255] = 0.f;      // pad edge contributes 0
    }
    #pragma unroll
    for (int q = 0; q < 4; ++q) {                  // W2 frags -> LDS (b128 copy)
        const int e = (q * 256 + t) * 8;
        *(short8*)(W2l + e) = *(const short8*)(W2fG + e);
    }
    if (t < 128) {
        const int i = t >> 6, h = t & 63;
        qrow[i][h] = Qg[(size_t)(i * 4 + b) * 16384 + r * 64 + h];
    }
    if (t >= 192) xl[t - 192] = xb[r * 64 + (t - 192)];

    // edge rows for this wave's two M-tiles
    const int kap0 = 64 * w + l31;
    const int kap1 = kap0 + 32;
    int s0 = (kap0 < r) ? kap0 : kap0 + 1; if (s0 > 255) s0 = 255;  // pad row
    int s1 = (kap1 < r) ? kap1 : kap1 + 1; if (s1 > 255) s1 = 255;

    // type-0 P gathers (8 frags = 32 VGPR), latency hides under staging
    short8 P000 = LD_P(0,0,s0), P001 = LD_P(0,1,s0), P002 = LD_P(0,2,s0), P003 = LD_P(0,3,s0);
    short8 P010 = LD_P(0,0,s1), P011 = LD_P(0,1,s1), P012 = LD_P(0,2,s1), P013 = LD_P(0,3,s1);

    const float bv00 = b2[l31],      bv01 = b2[32 + l31];
    const float bv10 = b2[64 + l31], bv11 = b2[96 + l31];

    __syncthreads();

    float psum0 = 0.f, psum1 = 0.f;   // per-lane agg partials, h = l31 / l31+32

    TILE2(0, 0, P000, P001, P002, P003, bv00, bv01);

    // type-1 s0 gathers: in flight under TILE2(0,1)'s MFMA work (T14)
    short8 Q000 = LD_P(1,0,s0), Q001 = LD_P(1,1,s0), Q002 = LD_P(1,2,s0), Q003 = LD_P(1,3,s0);

    TILE2(0, 1, P010, P011, P012, P013, bv00, bv01);

    // type-1 s1 gathers: in flight under TILE2(1,0)
    short8 Q010 = LD_P(1,0,s1), Q011 = LD_P(1,1,s1), Q012 = LD_P(1,2,s1), Q013 = LD_P(1,3,s1);

    TILE2(1, 0, Q000, Q001, Q002, Q003, bv10, bv11);
    TILE2(1, 1, Q010, Q011, Q012, Q013, bv10, bv11);

    // ---- reduce: lane-halves, then waves ----
    psum0 += __shfl_xor(psum0, 32, 64);
    psum1 += __shfl_xor(psum1, 32, 64);
    if (lh == 0) {
        red[w][l31]      = psum0;
        red[w][l31 + 32] = psum1;
    }
    __syncthreads();
    if (t < 64) aggl[t] = red[0][t] + red[1][t] + red[2][t] + red[3][t];
    __syncthreads();

    // ---- output MLP layer 1: aug(128) @ Wo1(128x64) ----
    {
        const float* src = (w < 2) ? (xl + w * 32) : (aggl + (w - 2) * 32);
        const float* Wp  = Wo1 + (w * 32) * 64 + lane;
        float s = 0.f;
        #pragma unroll
        for (int jj = 0; jj < 32; ++jj) s = fmaf(src[jj], Wp[jj * 64], s);
        red[w][lane] = s;
    }
    __syncthreads();
    if (t < 64)
        predl[t] = fmaxf(red[0][t] + red[1][t] + red[2][t] + red[3][t] + bo1[t], 0.f);
    __syncthreads();

    // ---- output MLP layer 2 + residual ----
    {
        const float* Wp = Wo2 + (w * 16) * 64 + lane;
        float s = 0.f;
        #pragma unroll
        for (int jj = 0; jj < 16; ++jj) s = fmaf(predl[w * 16 + jj], Wp[jj * 64], s);
        red[w][lane] = s;
    }
    __syncthreads();
    if (t < 64)
        out[((size_t)b * NB + r) * 64 + t] =
            xl[t] + fmaxf(red[0][t] + red[1][t] + red[2][t] + red[3][t] + bo2[t], 0.f);
}

// ---------------------------------------------------------------------------
extern "C" void kernel_launch(void* const* d_in, const int* in_sizes, int n_in,
                              void* d_out, int out_size, void* d_ws, size_t ws_size,
                              hipStream_t stream) {
    (void)in_sizes; (void)n_in; (void)out_size; (void)ws_size;

    const float* x    = (const float*)d_in[0];
    const float* rt   = (const float*)d_in[1];
    // d_in[2] = rel_rec, d_in[3] = rel_send: dense all-pairs one-hot, unused
    const float* W1   = (const float*)d_in[4];
    const float* b1   = (const float*)d_in[5];
    const float* W2   = (const float*)d_in[6];
    const float* b2   = (const float*)d_in[7];
    const float* Wo1  = (const float*)d_in[8];
    const float* bo1  = (const float*)d_in[9];
    const float* Wo2  = (const float*)d_in[10];
    const float* bo2  = (const float*)d_in[11];
    float* out = (float*)d_out;

    char* ws = (char*)d_ws;
    short* Pbf = (short*)ws;                 // 8*16384*2B  = 256 KiB
    float* Qg  = (float*)(ws + 262144);      // 8*16384*4B  = 512 KiB
    short* W2f = (short*)(ws + 786432);      // 16 KiB

    prep_kernel<<<17, 256, 0, stream>>>(x, W1, b1, W2, Pbf, Qg, W2f);
    main_kernel<<<BATCH * NB, 256, 0, stream>>>(x, rt, b2, Wo1, bo1, Wo2, bo2,
                                                Pbf, Qg, W2f, out);
}

// Round 10
// 22.508 us; speedup vs baseline: 2.1847x; 1.0529x over previous
//
#include <hip/hip_runtime.h>
#include <hip/hip_bf16.h>

#define BATCH 4
#define NB    256
#define NE    (NB*(NB-1))   // 65280

typedef short    short8 __attribute__((ext_vector_type(8)));
typedef float    f32x16 __attribute__((ext_vector_type(16)));

static __device__ __forceinline__ short f2bf(float x) {
    return __builtin_bit_cast(short, __float2bfloat16(x));   // RNE
}
static __device__ __forceinline__ float bf2f(short s) {
    unsigned u = ((unsigned)(unsigned short)s) << 16;
    return __builtin_bit_cast(float, u);
}
static __device__ __forceinline__ f32x16 splat16(float v) {
    f32x16 r;
    #pragma unroll
    for (int e = 0; e < 16; ++e) r[e] = v;
    return r;
}

#define MFMA(C, A, B) C = __builtin_amdgcn_mfma_f32_32x32x16_bf16(A, B, C, 0, 0, 0)

// W1 B-frag from LDS f32 (stride-64 scalar LDS reads: consecutive lanes ->
// consecutive banks, conflict-free; lane vs lane+32 2-way = free)
#define MK_BW(dst, BASE, K0, NT) do {                                          \
    const float* _p = W1l + (BASE) + (16*(K0) + 8*lh) * 64 + l31 + 32*(NT);    \
    short8 _v;                                                                 \
    _v[0]=f2bf(_p[0]);   _v[1]=f2bf(_p[64]);  _v[2]=f2bf(_p[128]);             \
    _v[3]=f2bf(_p[192]); _v[4]=f2bf(_p[256]); _v[5]=f2bf(_p[320]);             \
    _v[6]=f2bf(_p[384]); _v[7]=f2bf(_p[448]);                                  \
    (dst) = _v; } while (0)

// ---------------------------------------------------------------------------
// prep (17 wgs): unchanged from R7/R9 — proven.
// ---------------------------------------------------------------------------
__global__ __launch_bounds__(256) void prep_kernel(
    const float* __restrict__ x,   // [B][N][64]
    const float* __restrict__ W1,  // [2][128][64]
    const float* __restrict__ b1,  // [2][64]
    const float* __restrict__ W2,  // [2][64][64]
    short* __restrict__ Pbf,
    float* __restrict__ Qg,
    short* __restrict__ W2f)
{
    const int t    = threadIdx.x;
    const int lane = t & 63;
    const int w    = t >> 6;
    const int l31  = lane & 31;
    const int lh   = lane >> 5;
    const int blk  = blockIdx.x;

    __shared__ __align__(16) float W1l[8192];   // 32 KiB: W1[i] full
    __shared__ __align__(16) short xbf[8192];   // 16 KiB: 128 x-rows bf16, swizzled

    if (blk < 16) {
        const int i    = blk >> 3;
        const int b    = (blk >> 1) & 3;
        const int half = blk & 1;
        const int n0   = half * 128;
        const int ibb  = i * 4 + b;
        const float* xb = x + (size_t)b * NB * 64;

        #pragma unroll
        for (int q = 0; q < 8; ++q) {
            const int e = (q * 256 + t) * 4;
            *(float4*)(W1l + e) = *(const float4*)(W1 + (size_t)i * 8192 + e);
        }
        #pragma unroll
        for (int rep = 0; rep < 2; ++rep) {
            const int n  = (t >> 2) + 64 * rep;        // local row 0..127
            const int f0 = (t & 3) * 16;
            const float* src = xb + (n0 + n) * 64 + f0;
            float4 v0 = *(const float4*)(src);
            float4 v1 = *(const float4*)(src + 4);
            float4 v2 = *(const float4*)(src + 8);
            float4 v3 = *(const float4*)(src + 12);
            short8 s0 = { f2bf(v0.x), f2bf(v0.y), f2bf(v0.z), f2bf(v0.w),
                          f2bf(v1.x), f2bf(v1.y), f2bf(v1.z), f2bf(v1.w) };
            short8 s1 = { f2bf(v2.x), f2bf(v2.y), f2bf(v2.z), f2bf(v2.w),
                          f2bf(v3.x), f2bf(v3.y), f2bf(v3.z), f2bf(v3.w) };
            const int sw = (n & 7) << 4;
            *(short8*)((char*)xbf + n * 128 + ((f0 * 2)      ^ sw)) = s0;
            *(short8*)((char*)xbf + n * 128 + ((f0 * 2 + 16) ^ sw)) = s1;
        }
        __syncthreads();

        const int rloc = 32 * w + l31;
        const int swr  = (rloc & 7) << 4;
        const short8 XB0 = *(const short8*)((const char*)xbf + rloc*128 + ((16*lh)       ^ swr));
        const short8 XB1 = *(const short8*)((const char*)xbf + rloc*128 + ((32 + 16*lh)  ^ swr));
        const short8 XB2 = *(const short8*)((const char*)xbf + rloc*128 + ((64 + 16*lh)  ^ swr));
        const short8 XB3 = *(const short8*)((const char*)xbf + rloc*128 + ((96 + 16*lh)  ^ swr));

        {   // P, N-tile 0 (hh = l31)
            short8 B0, B1, B2, B3;
            MK_BW(B0, 0, 0, 0); MK_BW(B1, 0, 1, 0); MK_BW(B2, 0, 2, 0); MK_BW(B3, 0, 3, 0);
            f32x16 c = splat16(0.f);
            MFMA(c, XB0, B0); MFMA(c, XB1, B1); MFMA(c, XB2, B2); MFMA(c, XB3, B3);
            #pragma unroll
            for (int rg = 0; rg < 16; ++rg) {
                const int nn = n0 + 32*w + (rg & 3) + 8*(rg >> 2) + 4*lh;
                Pbf[(size_t)ibb*16384 + (l31 >> 3)*2048 + nn*8 + (l31 & 7)] = f2bf(c[rg]);
            }
        }
        {   // P, N-tile 1 (hh = l31 + 32)
            short8 B0, B1, B2, B3;
            MK_BW(B0, 0, 0, 1); MK_BW(B1, 0, 1, 1); MK_BW(B2, 0, 2, 1); MK_BW(B3, 0, 3, 1);
            f32x16 c = splat16(0.f);
            MFMA(c, XB0, B0); MFMA(c, XB1, B1); MFMA(c, XB2, B2); MFMA(c, XB3, B3);
            #pragma unroll
            for (int rg = 0; rg < 16; ++rg) {
                const int nn = n0 + 32*w + (rg & 3) + 8*(rg >> 2) + 4*lh;
                Pbf[(size_t)ibb*16384 + (4 + (l31 >> 3))*2048 + nn*8 + (l31 & 7)] = f2bf(c[rg]);
            }
        }
        {   // Q, N-tile 0
            short8 B0, B1, B2, B3;
            MK_BW(B0, 4096, 0, 0); MK_BW(B1, 4096, 1, 0); MK_BW(B2, 4096, 2, 0); MK_BW(B3, 4096, 3, 0);
            f32x16 c = splat16(0.f);
            MFMA(c, XB0, B0); MFMA(c, XB1, B1); MFMA(c, XB2, B2); MFMA(c, XB3, B3);
            const float b1v = b1[i * 64 + l31];
            #pragma unroll
            for (int rg = 0; rg < 16; ++rg) {
                const int nn = n0 + 32*w + (rg & 3) + 8*(rg >> 2) + 4*lh;
                Qg[(size_t)ibb*16384 + nn*64 + l31] = c[rg] + b1v;
            }
        }
        {   // Q, N-tile 1
            short8 B0, B1, B2, B3;
            MK_BW(B0, 4096, 0, 1); MK_BW(B1, 4096, 1, 1); MK_BW(B2, 4096, 2, 1); MK_BW(B3, 4096, 3, 1);
            f32x16 c = splat16(0.f);
            MFMA(c, XB0, B0); MFMA(c, XB1, B1); MFMA(c, XB2, B2); MFMA(c, XB3, B3);
            const float b1v = b1[i * 64 + 32 + l31];
            #pragma unroll
            for (int rg = 0; rg < 16; ++rg) {
                const int nn = n0 + 32*w + (rg & 3) + 8*(rg >> 2) + 4*lh;
                Qg[(size_t)ibb*16384 + nn*64 + 32 + l31] = c[rg] + b1v;
            }
        }
    } else {
        #pragma unroll
        for (int q = 0; q < 32; ++q) {
            const int e = q * 256 + t;             // == i*4096 + k*64 + n
            const int i = e >> 12, k = (e >> 6) & 63, n = e & 63;
            const float v = W2[e];
            const int k0 = k >> 4, j = k & 7, hm = (k >> 3) & 1;
            const int nt = n >> 5;
            W2f[(((i*2 + nt)*4 + k0)*64 + hm*32 + (n & 31))*8 + j] = f2bf(v);
        }
    }
}

// ---------------------------------------------------------------------------
// main: one wg per (b, receiver r); 256 threads = 4 waves. Register diet:
// sequential h-halves (one f32x16 acc live, not two), 4-frag P pipeline.
// Target total (VGPR+acc) <= ~128 for 4 wg/CU; (256,3) cap as guard.
// ---------------------------------------------------------------------------

// A2 frag: relu(bf2f(P) + qrow) -> bf16, k-elems h = 16*K0+8*lh+j
#define MK_A2(dst, PV, I, K0) do {                                             \
    float4 _q0 = *(const float4*)(&qrow[I][16*(K0) + 8*lh]);                   \
    float4 _q1 = *(const float4*)(&qrow[I][16*(K0) + 8*lh + 4]);               \
    short8 _v;                                                                 \
    _v[0] = f2bf(fmaxf(bf2f((PV)[0]) + _q0.x, 0.f));                           \
    _v[1] = f2bf(fmaxf(bf2f((PV)[1]) + _q0.y, 0.f));                           \
    _v[2] = f2bf(fmaxf(bf2f((PV)[2]) + _q0.z, 0.f));                           \
    _v[3] = f2bf(fmaxf(bf2f((PV)[3]) + _q0.w, 0.f));                           \
    _v[4] = f2bf(fmaxf(bf2f((PV)[4]) + _q1.x, 0.f));                           \
    _v[5] = f2bf(fmaxf(bf2f((PV)[5]) + _q1.y, 0.f));                           \
    _v[6] = f2bf(fmaxf(bf2f((PV)[6]) + _q1.z, 0.f));                           \
    _v[7] = f2bf(fmaxf(bf2f((PV)[7]) + _q1.w, 0.f));                           \
    (dst) = _v; } while (0)

// epilogue quad into ONE psum (h-halves processed sequentially)
#define EPI_Q(C, PS, I, ET, QD) do {                                           \
    float4 _rq = *(const float4*)(&rt2[I][64*w + 32*(ET) + 8*(QD) + 4*lh]);    \
    PS += fmaxf((C)[4*(QD)],   0.f) * _rq.x;                                   \
    PS += fmaxf((C)[4*(QD)+1], 0.f) * _rq.y;                                   \
    PS += fmaxf((C)[4*(QD)+2], 0.f) * _rq.z;                                   \
    PS += fmaxf((C)[4*(QD)+3], 0.f) * _rq.w; } while (0)

// one (edge-type I, edge-tile ET) macro-tile, sequential h-halves:
// build 4 A2 frags once; half A (w frags 0-3 -> psum0); half B (4-7 -> psum1)
#define TILE2(I, ET, PA, PB, PC, PD, BVA, BVB) do {                            \
    short8 _a0, _a1, _a2, _a3;                                                 \
    MK_A2(_a0, PA, I, 0); MK_A2(_a1, PB, I, 1);                                \
    MK_A2(_a2, PC, I, 2); MK_A2(_a3, PD, I, 3);                                \
    {                                                                          \
        f32x16 _c = splat16(BVA);                                              \
        MFMA(_c, _a0, *(const short8*)(W2l + (((I)*8 + 0)*64 + lane)*8));      \
        MFMA(_c, _a1, *(const short8*)(W2l + (((I)*8 + 1)*64 + lane)*8));      \
        MFMA(_c, _a2, *(const short8*)(W2l + (((I)*8 + 2)*64 + lane)*8));      \
        MFMA(_c, _a3, *(const short8*)(W2l + (((I)*8 + 3)*64 + lane)*8));      \
        EPI_Q(_c, psum0, I, ET, 0); EPI_Q(_c, psum0, I, ET, 1);                \
        EPI_Q(_c, psum0, I, ET, 2); EPI_Q(_c, psum0, I, ET, 3);                \
    }                                                                          \
    {                                                                          \
        f32x16 _c = splat16(BVB);                                              \
        MFMA(_c, _a0, *(const short8*)(W2l + (((I)*8 + 4)*64 + lane)*8));      \
        MFMA(_c, _a1, *(const short8*)(W2l + (((I)*8 + 5)*64 + lane)*8));      \
        MFMA(_c, _a2, *(const short8*)(W2l + (((I)*8 + 6)*64 + lane)*8));      \
        MFMA(_c, _a3, *(const short8*)(W2l + (((I)*8 + 7)*64 + lane)*8));      \
        EPI_Q(_c, psum1, I, ET, 0); EPI_Q(_c, psum1, I, ET, 1);                \
        EPI_Q(_c, psum1, I, ET, 2); EPI_Q(_c, psum1, I, ET, 3);                \
    } } while (0)

#define LD_P(I, K0, S) \
    (*(const short8*)(PbfG + ((size_t)((I)*4+b)*8 + 2*(K0)+lh)*2048 + (size_t)(S)*8))

__global__ __launch_bounds__(256, 3) void main_kernel(
    const float* __restrict__ x,
    const float* __restrict__ rel_type, // [B][E][2]
    const float* __restrict__ b2,       // [2][64]
    const float* __restrict__ Wo1,      // [128][64]
    const float* __restrict__ bo1,
    const float* __restrict__ Wo2,      // [64][64]
    const float* __restrict__ bo2,
    const short* __restrict__ PbfG,
    const float* __restrict__ Qg,
    const short* __restrict__ W2fG,
    float* __restrict__ out)
{
    const int b    = blockIdx.x >> 8;
    const int r    = blockIdx.x & 255;
    const int t    = threadIdx.x;
    const int lane = t & 63;
    const int w    = t >> 6;
    const int l31  = lane & 31;
    const int lh   = lane >> 5;

    __shared__ __align__(16) short W2l[8192];      // 16 KiB
    __shared__ __align__(16) float rt2[2][256];
    __shared__ __align__(16) float qrow[2][64];
    __shared__ __align__(16) float red[4][64];
    __shared__ __align__(16) float xl[64];
    __shared__ __align__(16) float aggl[64];
    __shared__ __align__(16) float predl[64];

    const float* xb = x + (size_t)b * NB * 64;

    // ---- staging ----
    if (t < 255) {
        const float2 pv = *(const float2*)(rel_type + ((size_t)b * NE + (size_t)r * 255 + t) * 2);
        rt2[0][t] = pv.x;
        rt2[1][t] = pv.y;
    } else {
        rt2[0][255] = 0.f; rt2[1][255] = 0.f;      // pad edge contributes 0
    }
    #pragma unroll
    for (int q = 0; q < 4; ++q) {                  // W2 frags -> LDS (b128 copy)
        const int e = (q * 256 + t) * 8;
        *(short8*)(W2l + e) = *(const short8*)(W2fG + e);
    }
    if (t < 128) {
        const int i = t >> 6, h = t & 63;
        qrow[i][h] = Qg[(size_t)(i * 4 + b) * 16384 + r * 64 + h];
    }
    if (t >= 192) xl[t - 192] = xb[r * 64 + (t - 192)];

    // edge rows for this wave's two M-tiles
    const int kap0 = 64 * w + l31;
    const int kap1 = kap0 + 32;
    int s0 = (kap0 < r) ? kap0 : kap0 + 1; if (s0 > 255) s0 = 255;  // pad row
    int s1 = (kap1 < r) ? kap1 : kap1 + 1; if (s1 > 255) s1 = 255;

    // first P set (type 0, s0): 4 frags = 16 VGPR
    short8 P00 = LD_P(0,0,s0), P01 = LD_P(0,1,s0), P02 = LD_P(0,2,s0), P03 = LD_P(0,3,s0);

    const float bv00 = b2[l31],      bv01 = b2[32 + l31];
    const float bv10 = b2[64 + l31], bv11 = b2[96 + l31];

    __syncthreads();

    float psum0 = 0.f, psum1 = 0.f;   // per-lane agg partials, h = l31 / l31+32

    // issue next set before compute (T14): latency hides under MFMA
    short8 P10 = LD_P(0,0,s1), P11 = LD_P(0,1,s1), P12 = LD_P(0,2,s1), P13 = LD_P(0,3,s1);
    TILE2(0, 0, P00, P01, P02, P03, bv00, bv01);

    P00 = LD_P(1,0,s0); P01 = LD_P(1,1,s0); P02 = LD_P(1,2,s0); P03 = LD_P(1,3,s0);
    TILE2(0, 1, P10, P11, P12, P13, bv00, bv01);

    P10 = LD_P(1,0,s1); P11 = LD_P(1,1,s1); P12 = LD_P(1,2,s1); P13 = LD_P(1,3,s1);
    TILE2(1, 0, P00, P01, P02, P03, bv10, bv11);

    TILE2(1, 1, P10, P11, P12, P13, bv10, bv11);

    // ---- reduce: lane-halves, then waves ----
    psum0 += __shfl_xor(psum0, 32, 64);
    psum1 += __shfl_xor(psum1, 32, 64);
    if (lh == 0) {
        red[w][l31]      = psum0;
        red[w][l31 + 32] = psum1;
    }
    __syncthreads();
    if (t < 64) aggl[t] = red[0][t] + red[1][t] + red[2][t] + red[3][t];
    __syncthreads();

    // ---- output MLP layer 1: aug(128) @ Wo1(128x64) ----
    {
        const float* src = (w < 2) ? (xl + w * 32) : (aggl + (w - 2) * 32);
        const float* Wp  = Wo1 + (w * 32) * 64 + lane;
        float s = 0.f;
        #pragma unroll
        for (int jj = 0; jj < 32; ++jj) s = fmaf(src[jj], Wp[jj * 64], s);
        red[w][lane] = s;
    }
    __syncthreads();
    if (t < 64)
        predl[t] = fmaxf(red[0][t] + red[1][t] + red[2][t] + red[3][t] + bo1[t], 0.f);
    __syncthreads();

    // ---- output MLP layer 2 + residual ----
    {
        const float* Wp = Wo2 + (w * 16) * 64 + lane;
        float s = 0.f;
        #pragma unroll
        for (int jj = 0; jj < 16; ++jj) s = fmaf(predl[w * 16 + jj], Wp[jj * 64], s);
        red[w][lane] = s;
    }
    __syncthreads();
    if (t < 64)
        out[((size_t)b * NB + r) * 64 + t] =
            xl[t] + fmaxf(red[0][t] + red[1][t] + red[2][t] + red[3][t] + bo2[t], 0.f);
}

// ---------------------------------------------------------------------------
extern "C" void kernel_launch(void* const* d_in, const int* in_sizes, int n_in,
                              void* d_out, int out_size, void* d_ws, size_t ws_size,
                              hipStream_t stream) {
    (void)in_sizes; (void)n_in; (void)out_size; (void)ws_size;

    const float* x    = (const float*)d_in[0];
    const float* rt   = (const float*)d_in[1];
    // d_in[2] = rel_rec, d_in[3] = rel_send: dense all-pairs one-hot, unused
    const float* W1   = (const float*)d_in[4];
    const float* b1   = (const float*)d_in[5];
    const float* W2   = (const float*)d_in[6];
    const float* b2   = (const float*)d_in[7];
    const float* Wo1  = (const float*)d_in[8];
    const float* bo1  = (const float*)d_in[9];
    const float* Wo2  = (const float*)d_in[10];
    const float* bo2  = (const float*)d_in[11];
    float* out = (float*)d_out;

    char* ws = (char*)d_ws;
    short* Pbf = (short*)ws;                 // 8*16384*2B  = 256 KiB
    float* Qg  = (float*)(ws + 262144);      // 8*16384*4B  = 512 KiB
    short* W2f = (short*)(ws + 786432);      // 16 KiB

    prep_kernel<<<17, 256, 0, stream>>>(x, W1, b1, W2, Pbf, Qg, W2f);
    main_kernel<<<BATCH * NB, 256, 0, stream>>>(x, rt, b2, Wo1, bo1, Wo2, bo2,
                                                Pbf, Qg, W2f, out);
}